// Round 20
// baseline (136.989 us; speedup 1.0000x reference)
//
#include <hip/hip_runtime.h>
#include <hip/hip_fp16.h>

#define LM 20

// ---------------- ws layout (bytes) ----------------
#define OFF_Q0    16777216ull
#define OFF_Q1    33554432ull
#define OFF_ZB    33554432ull             // Zb overwrites Q1 after G3
#define OFF_EIG   50331648ull
#define OFF_DIFFP (OFF_EIG + 4096ull)
#define OFF_OFFP  (OFF_DIFFP + 1024ull)
#define OFF_TRP   (OFF_OFFP + 1024ull)
#define OFF_SMALL (OFF_TRP + 1024ull)

typedef unsigned short ushort_t;
typedef short bf16x8 __attribute__((ext_vector_type(8)));
typedef float f32x4 __attribute__((ext_vector_type(4)));

static __device__ __forceinline__ ushort_t f2bf(float f) {
  unsigned u = __float_as_uint(f);
  unsigned r = (u + 0x7fffu + ((u >> 16) & 1u)) >> 16;
  return (ushort_t)r;
}
static __device__ __forceinline__ unsigned packbf(float a, float b) {
  return (unsigned)f2bf(a) | ((unsigned)f2bf(b) << 16);
}
static __device__ __forceinline__ float bflo(unsigned u) { return __uint_as_float(u << 16); }
static __device__ __forceinline__ float bfhi(unsigned u) { return __uint_as_float(u & 0xffff0000u); }
static __device__ __forceinline__ float b2f(ushort_t u) { return __uint_as_float(((unsigned)u) << 16); }
static __device__ __forceinline__ __half2 u2h2(unsigned u) { __half2 r; *reinterpret_cast<unsigned*>(&r) = u; return r; }
static __device__ __forceinline__ unsigned packh2(float a, float b) {
  return (unsigned)__half_as_ushort(__float2half_rn(a)) |
         ((unsigned)__half_as_ushort(__float2half_rn(b)) << 16);
}

// ---------------- MFMA GEMM, 128x128 tile, BK=64, 128 batches (split bases at b=64) ----------------
template<bool ABF, int BMODE, bool INITP, bool REDUCE>
__global__ __launch_bounds__(256) void gemm_mfma(
    const void* __restrict__ A0, const void* __restrict__ A1, size_t sA,
    const void* __restrict__ B0, const void* __restrict__ B1, size_t sB,
    void* __restrict__ Cbase, size_t sC,
    const float* __restrict__ Zr0, const float* __restrict__ Zr1, size_t sZr,
    double* __restrict__ smallp, double* __restrict__ diffP,
    double* __restrict__ offP, double* __restrict__ trP)
{
  __shared__ ushort_t At[128][72];
  __shared__ ushort_t Bt[128][72];
  __shared__ float redsh[4][3];
  const int t = threadIdx.x;
  if (INITP && blockIdx.x == 0 && blockIdx.y == 0 && blockIdx.z == 0) {
    if (t < 2) smallp[t] = 0.0;
    if (t < 128) { diffP[t] = 0.0; offP[t] = 0.0; trP[t] = 0.0; }
  }
  const int b = blockIdx.z;
  const int bl = (b < 64) ? b : b - 64;
  const void* Ab_ = (b < 64) ? A0 : A1;
  const void* Bb_ = (b < 64) ? B0 : B1;
  const int tm = blockIdx.y * 128, tn = blockIdx.x * 128;
  const int w = t >> 6, l = t & 63;
  const int wr = w >> 1, wc = w & 1;
  const int fr = l & 15, kc = l >> 4;

  f32x4 acc[4][4] = {};

  for (int s4 = 0; s4 < 4; ++s4) {
    const int k0 = s4 << 6;
    // ---- stage A: 128x64, 4 uint4-chunks per thread ----
    #pragma unroll
    for (int cc = 0; cc < 4; ++cc) {
      int c = t + cc * 256;
      int row = c >> 3, q = c & 7;
      if (ABF) {
        const ushort_t* Ap = (const ushort_t*)Ab_ + (size_t)bl * sA + (size_t)(tm + row) * 256 + k0 + q * 8;
        *(uint4*)&At[row][q * 8] = *(const uint4*)Ap;
      } else {
        const float* Ap = (const float*)Ab_ + (size_t)bl * sA + (size_t)(tm + row) * 256 + k0 + q * 8;
        float4 f0 = *(const float4*)Ap, f1 = *(const float4*)(Ap + 4);
        uint4 u;
        u.x = packbf(f0.x, f0.y); u.y = packbf(f0.z, f0.w);
        u.z = packbf(f1.x, f1.y); u.w = packbf(f1.z, f1.w);
        *(uint4*)&At[row][q * 8] = u;
      }
    }
    // ---- stage B ----
    if (BMODE == 1) {
      #pragma unroll
      for (int cc = 0; cc < 4; ++cc) {
        int c = t + cc * 256;
        int row = c >> 3, q = c & 7;
        const float* Bp = (const float*)Bb_ + (size_t)bl * sB + (size_t)(tn + row) * 256 + k0 + q * 8;
        float4 f0 = *(const float4*)Bp, f1 = *(const float4*)(Bp + 4);
        uint4 u;
        u.x = packbf(f0.x, f0.y); u.y = packbf(f0.z, f0.w);
        u.z = packbf(f1.x, f1.y); u.w = packbf(f1.z, f1.w);
        *(uint4*)&Bt[row][q * 8] = u;
      }
    } else {
      // B stored [K][N] fp32: Bt[n][kp] packed bf16 pair of rows 2kp,2kp+1
      int kp = t & 31, c = t >> 5;     // kp: k-pair 0..31; c: 16-col group 0..7
      const float* Bp0 = (const float*)Bb_ + (size_t)bl * sB + (size_t)(k0 + 2 * kp) * 256 + tn + c * 16;
      const float* Bp1 = Bp0 + 256;
      float4 a0 = *(const float4*)Bp0, a1 = *(const float4*)(Bp0 + 4);
      float4 a2 = *(const float4*)(Bp0 + 8), a3 = *(const float4*)(Bp0 + 12);
      float4 c0v = *(const float4*)Bp1, c1v = *(const float4*)(Bp1 + 4);
      float4 c2v = *(const float4*)(Bp1 + 8), c3v = *(const float4*)(Bp1 + 12);
      float lo[16] = {a0.x,a0.y,a0.z,a0.w, a1.x,a1.y,a1.z,a1.w,
                      a2.x,a2.y,a2.z,a2.w, a3.x,a3.y,a3.z,a3.w};
      float hi[16] = {c0v.x,c0v.y,c0v.z,c0v.w, c1v.x,c1v.y,c1v.z,c1v.w,
                      c2v.x,c2v.y,c2v.z,c2v.w, c3v.x,c3v.y,c3v.z,c3v.w};
      unsigned* Bd = (unsigned*)&Bt[0][0];
      #pragma unroll
      for (int i = 0; i < 16; ++i) {
        int n = c * 16 + i;
        Bd[n * 36 + kp] = packbf(lo[i], hi[i]);
      }
    }
    __syncthreads();
    #pragma unroll
    for (int kk = 0; kk < 2; ++kk) {
      bf16x8 af[4], bfv[4];
      #pragma unroll
      for (int i = 0; i < 4; ++i) af[i] = *(const bf16x8*)&At[wr * 64 + i * 16 + fr][kk * 32 + kc * 8];
      #pragma unroll
      for (int jj = 0; jj < 4; ++jj) bfv[jj] = *(const bf16x8*)&Bt[wc * 64 + jj * 16 + fr][kk * 32 + kc * 8];
      #pragma unroll
      for (int i = 0; i < 4; ++i) {
        #pragma unroll
        for (int jj = 0; jj < 4; ++jj) {
          acc[i][jj] = __builtin_amdgcn_mfma_f32_16x16x32_bf16(af[i], bfv[jj], acc[i][jj], 0, 0, 0);
        }
      }
    }
    __syncthreads();
  }

  ushort_t* Cp = (ushort_t*)Cbase + (size_t)b * sC;
  #pragma unroll
  for (int i = 0; i < 4; ++i) {
    #pragma unroll
    for (int q = 0; q < 4; ++q) {
      size_t rbase = (size_t)(tm + wr * 64 + i * 16 + kc * 4 + q) * 256;
      #pragma unroll
      for (int jj = 0; jj < 4; ++jj) {
        Cp[rbase + tn + wc * 64 + jj * 16 + fr] = f2bf(acc[i][jj][q]);
      }
    }
  }

  if (REDUCE) {
    const float* Zr_ = ((b < 64) ? Zr0 : Zr1) + (size_t)bl * sZr;
    float pd = 0.f, po = 0.f, ptr = 0.f;
    #pragma unroll
    for (int i = 0; i < 4; ++i) {
      #pragma unroll
      for (int q = 0; q < 4; ++q) {
        int row = tm + wr * 64 + i * 16 + kc * 4 + q;
        const float* ZrRow = Zr_ + (size_t)row * 256 + tn + wc * 64;
        #pragma unroll
        for (int jj = 0; jj < 4; ++jj) {
          int col = tn + wc * 64 + jj * 16 + fr;
          float c = acc[i][jj][q];
          float zr = ZrRow[jj * 16 + fr];
          bool diag = (row == col);
          pd += fabsf(c - (diag ? 1.0f : 0.0f));
          po += diag ? 0.0f : fabsf(c);
          ptr += fabsf(c - zr);
        }
      }
    }
    #pragma unroll
    for (int off = 32; off > 0; off >>= 1) {
      pd += __shfl_down(pd, off);
      po += __shfl_down(po, off);
      ptr += __shfl_down(ptr, off);
    }
    if (l == 0) { redsh[w][0] = pd; redsh[w][1] = po; redsh[w][2] = ptr; }
    __syncthreads();
    if (t == 0) {
      atomicAdd(&diffP[b], (double)(redsh[0][0] + redsh[1][0] + redsh[2][0] + redsh[3][0]));
      atomicAdd(&offP[b],  (double)(redsh[0][1] + redsh[1][1] + redsh[2][1] + redsh[3][1]));
      atomicAdd(&trP[b],   (double)(redsh[0][2] + redsh[1][2] + redsh[2][2] + redsh[3][2]));
    }
  }
}

// ====== MEGA: lanczos (0..127, fused symmetrize) | cp (128..243) | sreg (244..247) | head (248..255) ======
struct LanSh {
  ushort_t Zl[256][260];   // padded bf16 matrix
  unsigned vpack[128];
  float wtmp[4][256];
  float red2[4][2];
  float red1[16];
  float alpha[LM];
  float betaArr[LM + 1];
  float beta2arr[LM + 1];
};
struct CpSh { float Bsh[4][256][4]; float Csh[4][256][4]; double red[4][256]; };
struct SregSh { double red[4][256]; };
struct HeadSh {
  float Wl[32][258];
  float seedsl[8][256];
  float hbuf2[8][128];
  float tri[8][4][3];
  float cps[8][4];
  float seds[8][4];
};
union MegaSh { LanSh lan; CpSh cp; SregSh sreg; HeadSh head; };

__global__ __launch_bounds__(1024, 1) void mega_kernel(
    float* __restrict__ eig,
    const float* __restrict__ ti, const ushort_t* __restrict__ Zb,
    const float* __restrict__ cpA, const float* __restrict__ cpB, const float* __restrict__ cpC,
    double* __restrict__ smallp,
    const float* __restrict__ S1, const float* __restrict__ S2,
    const float* __restrict__ S3, const float* __restrict__ S4,
    const float* __restrict__ seed_ic, const float* __restrict__ seed_sir,
    const float* __restrict__ seed_icc, const float* __restrict__ seed_sirc,
    const float* __restrict__ scalars,
    const float* __restrict__ cpW1, const float* __restrict__ cpb1,
    const float* __restrict__ cpw2, const float* __restrict__ cpb2,
    const float* __restrict__ sW1, const float* __restrict__ sb1,
    const float* __restrict__ sw2, const float* __restrict__ sb2,
    const float* __restrict__ fW1, const float* __restrict__ fb1,
    const float* __restrict__ fw2, const float* __restrict__ fb2,
    float* __restrict__ out)
{
  __shared__ MegaSh sh;
  const int bid = blockIdx.x;
  const int t = threadIdx.x;

  if (bid < 128) {
    // ---------------- Lanczos with in-block symmetrize ----------------
    int lane = t & 63, w16 = t >> 6;
    int r = t & 255, h = t >> 8;
    int mtx = bid;
    const ushort_t* Zm = Zb + (size_t)mtx * 65536;

    #pragma unroll
    for (int it = 0; it < 16; ++it) {
      int idx = t + it * 1024;
      int row = idx >> 6, c4 = (idx & 63) << 2;
      *(uint2*)&sh.lan.Zl[row][c4] = *(const uint2*)(Zm + (size_t)row * 256 + c4);
    }
    __syncthreads();

    const float SC = 0.5f * 0.015625f;
    unsigned m[32];
    #pragma unroll
    for (int q = 0; q < 32; ++q) {
      int c0 = h * 64 + 2 * q;
      unsigned a = *(const unsigned*)&sh.lan.Zl[r][c0];
      float b0v = b2f(sh.lan.Zl[c0][r]);
      float b1v = b2f(sh.lan.Zl[c0 + 1][r]);
      m[q] = packh2((bflo(a) + b0v) * SC, (bfhi(a) + b1v) * SC);
    }
    __syncthreads();

    unsigned u0 = (unsigned)r * 1103515245u + 12345u;
    float r0v = 0.05f + (float)((u0 >> 9) & 0x7FFF) * (1.0f / 32768.0f);
    float vt = 0.0f, vprev = 0.0f;
    {
      float nv = r0v * r0v;
      #pragma unroll
      for (int off = 32; off > 0; off >>= 1) nv += __shfl_down(nv, off);
      if (lane == 0) sh.lan.red1[w16] = nv;
    }
    __syncthreads();
    {
      float nrm2 = sh.lan.red1[0] + sh.lan.red1[1] + sh.lan.red1[2] + sh.lan.red1[3];
      vt = r0v * rsqrtf(nrm2);
      if (h == 0) {
        float vo = __shfl_down(vt, 1);
        if ((lane & 1) == 0) sh.lan.vpack[t >> 1] = packh2(vt, vo);
      }
    }
    __syncthreads();

    const uint4* vp4 = (const uint4*)sh.lan.vpack;
    float2* red2 = (float2*)&sh.lan.red2[0][0];
    float beta_prev = 0.0f;
    int meff = LM;
    for (int j = 0; j < LM; ++j) {
      __half2 h0v = u2h2(0u), h1v = u2h2(0u), h2v = u2h2(0u), h3v = u2h2(0u);
      #pragma unroll
      for (int q = 0; q < 8; ++q) {
        uint4 vu = vp4[h * 8 + q];
        h0v = __hfma2(u2h2(m[4 * q + 0]), u2h2(vu.x), h0v);
        h1v = __hfma2(u2h2(m[4 * q + 1]), u2h2(vu.y), h1v);
        h2v = __hfma2(u2h2(m[4 * q + 2]), u2h2(vu.z), h2v);
        h3v = __hfma2(u2h2(m[4 * q + 3]), u2h2(vu.w), h3v);
      }
      float2 f0 = __half22float2(h0v), f1 = __half22float2(h1v);
      float2 f2 = __half22float2(h2v), f3 = __half22float2(h3v);
      sh.lan.wtmp[h][r] = ((f0.x + f0.y) + (f1.x + f1.y)) + ((f2.x + f2.y) + (f3.x + f3.y));
      float wt = 0.0f;
      __syncthreads();                                      // B1
      if (h == 0) {
        wt = sh.lan.wtmp[0][r] + sh.lan.wtmp[1][r] + sh.lan.wtmp[2][r] + sh.lan.wtmp[3][r];
        float s1 = wt * vt, s3 = wt * wt;
        #pragma unroll
        for (int off = 32; off > 0; off >>= 1) {
          s1 += __shfl_down(s1, off);
          s3 += __shfl_down(s3, off);
        }
        if (lane == 0) red2[w16] = make_float2(s1, s3);
      }
      __syncthreads();                                      // B2
      float2 p0 = red2[0], p1 = red2[1], p2 = red2[2], p3 = red2[3];
      float S1v = ((p0.x + p1.x) + (p2.x + p3.x));
      float S3v = ((p0.y + p1.y) + (p2.y + p3.y));
      float bn2 = S3v - S1v * S1v - beta_prev * beta_prev;
      float bn = sqrtf(fmaxf(bn2, 1e-30f));
      if (t == 0) { sh.lan.alpha[j] = S1v; sh.lan.betaArr[j + 1] = bn; sh.lan.beta2arr[j + 1] = bn * bn; }
      if (bn < 1e-6f * (fabsf(S1v) + 1.0f)) { meff = j + 1; break; }
      if (h == 0) {
        float wn = (wt - S1v * vt - beta_prev * vprev) / bn;
        vprev = vt; vt = wn;
        float vo = __shfl_down(vt, 1);
        if ((lane & 1) == 0) sh.lan.vpack[t >> 1] = packh2(vt, vo);
      }
      beta_prev = bn;
      __syncthreads();                                      // B3
    }
    __syncthreads();

    if (w16 < 4) {
      float lo = 1e30f, hi = -1e30f;
      for (int i = 0; i < meff; ++i) {
        float bl = (i > 0) ? sh.lan.betaArr[i] : 0.0f;
        float bu = (i + 1 < meff) ? sh.lan.betaArr[i + 1] : 0.0f;
        lo = fminf(lo, sh.lan.alpha[i] - bl - bu);
        hi = fmaxf(hi, sh.lan.alpha[i] + bl + bu);
      }
      int q = w16 + 1; if (q > meff - 1) q = meff - 1;
      #pragma unroll
      for (int rr = 0; rr < 3; ++rr) {
        float step = (hi - lo) * (1.0f / 65.0f);
        float mid = lo + step * (float)(lane + 1);
        int cnt = 0;
        float d = sh.lan.alpha[0] - mid;
        if (fabsf(d) < 1e-20f) d = -1e-20f;
        cnt += (d < 0.0f);
        for (int i = 1; i < meff; ++i) {
          d = sh.lan.alpha[i] - mid - sh.lan.beta2arr[i] / d;
          if (fabsf(d) < 1e-20f) d = -1e-20f;
          cnt += (d < 0.0f);
        }
        unsigned long long mask = __ballot(cnt >= q + 1);
        if (mask == 0ULL) {
          lo = lo + step * 64.0f;
        } else {
          int idx = __ffsll(mask) - 1;
          float nlo = lo + step * (float)idx;
          hi = lo + step * (float)(idx + 1);
          lo = nlo;
        }
      }
      if (lane == 0) eig[mtx * 4 + w16] = 32.0f * (lo + hi);
    }
  } else if (bid < 244) {
    int g = t >> 8, tid = t & 255;
    int unit = (bid - 128) * 4 + g;
    bool live = (unit < 384);
    int b = live ? (unit / 6) : 0;
    int i = live ? (unit - b * 6) : 0;
    float (*Bsh)[4] = sh.cp.Bsh[g];
    float (*Csh)[4] = sh.cp.Csh[g];
    double* red = sh.cp.red[g];
    if (live) {
      *(float4*)&Bsh[tid][0] = *(const float4*)(cpB + ((size_t)b * 256 + tid) * 4);
      *(float4*)&Csh[tid][0] = *(const float4*)(cpC + ((size_t)b * 256 + tid) * 4);
    }
    float a0 = live ? cpA[((size_t)b * 6 + i) * 4 + 0] : 0.f;
    float a1 = live ? cpA[((size_t)b * 6 + i) * 4 + 1] : 0.f;
    float a2 = live ? cpA[((size_t)b * 6 + i) * 4 + 2] : 0.f;
    float a3 = live ? cpA[((size_t)b * 6 + i) * 4 + 3] : 0.f;
    __syncthreads();
    double acc0 = 0, acc1 = 0;
    if (live) {
      float c0 = Csh[tid][0], c1 = Csh[tid][1], c2 = Csh[tid][2], c3 = Csh[tid][3];
      if (i < 4) {
        const float* T = ti + ((size_t)b * 6 + i) * 65536;
        #pragma unroll 4
        for (int j = 0; j < 256; j += 2) {
          float4 bj0 = *(const float4*)&Bsh[j][0];
          float4 bj1 = *(const float4*)&Bsh[j + 1][0];
          float r0 = a0 * bj0.x * c0 + a1 * bj0.y * c1 + a2 * bj0.z * c2 + a3 * bj0.w * c3;
          float r1 = a0 * bj1.x * c0 + a1 * bj1.y * c1 + a2 * bj1.z * c2 + a3 * bj1.w * c3;
          float d0 = r0 - T[(size_t)j * 256 + tid];
          float d1 = r1 - T[(size_t)(j + 1) * 256 + tid];
          acc0 += (double)d0 * (double)d0;
          acc1 += (double)d1 * (double)d1;
        }
      } else {
        const ushort_t* T = Zb + (size_t)((i == 4) ? b : 64 + b) * 65536;
        #pragma unroll 4
        for (int j = 0; j < 256; j += 2) {
          float4 bj0 = *(const float4*)&Bsh[j][0];
          float4 bj1 = *(const float4*)&Bsh[j + 1][0];
          float r0 = a0 * bj0.x * c0 + a1 * bj0.y * c1 + a2 * bj0.z * c2 + a3 * bj0.w * c3;
          float r1 = a0 * bj1.x * c0 + a1 * bj1.y * c1 + a2 * bj1.z * c2 + a3 * bj1.w * c3;
          float d0 = r0 - b2f(T[(size_t)j * 256 + tid]);
          float d1 = r1 - b2f(T[(size_t)(j + 1) * 256 + tid]);
          acc0 += (double)d0 * (double)d0;
          acc1 += (double)d1 * (double)d1;
        }
      }
    }
    red[tid] = acc0 + acc1; __syncthreads();
    #pragma unroll
    for (int s = 128; s > 0; s >>= 1) { if (tid < s) red[tid] += red[tid + s]; __syncthreads(); }
    if (live && tid == 0) atomicAdd(&smallp[0], red[0]);
  } else if (bid < 248) {
    int g = t >> 8, tid = t & 255;
    int slot = (bid - 244) * 4 + g;
    int mnum = slot >> 2, quarter = slot & 3;
    const float* S = (mnum == 0) ? S1 : (mnum == 1) ? S2 : (mnum == 2) ? S3 : S4;
    double* red = sh.sreg.red[g];
    double tot = 0;
    int base = quarter * 16384;
    #pragma unroll 4
    for (int e = base + tid; e < base + 16384; e += 256) {
      int i = e >> 8, j = e & 255;
      float a = S[e];
      tot += (double)fabsf(a - (i == j ? 1.0f : 0.0f));
      if (i != j) tot += (double)fabsf(a);
    }
    red[tid] = tot; __syncthreads();
    #pragma unroll
    for (int s = 128; s > 0; s >>= 1) { if (tid < s) red[tid] += red[tid + s]; __syncthreads(); }
    if (tid == 0) atomicAdd(&smallp[1], -red[0] / 65536.0);
  } else {
    HeadSh& H = sh.head;
    const int b0 = (bid - 248) * 8;
    const int g = t >> 6, l = t & 63;
    const bool act = g < 8;
    const int b = b0 + (act ? g : 0);
    if (act) {
      if (l < 4) {
        float s = 0;
        #pragma unroll
        for (int i = 0; i < 6; ++i) s += cpA[((size_t)b * 6 + i) * 4 + l];
        H.tri[g][l][0] = s * (1.0f / 6.0f);
      }
      float4 sB = make_float4(0,0,0,0), sC = make_float4(0,0,0,0);
      for (int j = l; j < 256; j += 64) {
        float4 v = *(const float4*)(cpB + ((size_t)b * 256 + j) * 4);
        sB.x += v.x; sB.y += v.y; sB.z += v.z; sB.w += v.w;
        float4 w = *(const float4*)(cpC + ((size_t)b * 256 + j) * 4);
        sC.x += w.x; sC.y += w.y; sC.z += w.z; sC.w += w.w;
      }
      #pragma unroll
      for (int off = 32; off > 0; off >>= 1) {
        sB.x += __shfl_down(sB.x, off); sB.y += __shfl_down(sB.y, off);
        sB.z += __shfl_down(sB.z, off); sB.w += __shfl_down(sB.w, off);
        sC.x += __shfl_down(sC.x, off); sC.y += __shfl_down(sC.y, off);
        sC.z += __shfl_down(sC.z, off); sC.w += __shfl_down(sC.w, off);
      }
      if (l == 0) {
        H.tri[g][0][1] = sB.x * (1.0f/256.0f); H.tri[g][1][1] = sB.y * (1.0f/256.0f);
        H.tri[g][2][1] = sB.z * (1.0f/256.0f); H.tri[g][3][1] = sB.w * (1.0f/256.0f);
        H.tri[g][0][2] = sC.x * (1.0f/256.0f); H.tri[g][1][2] = sC.y * (1.0f/256.0f);
        H.tri[g][2][2] = sC.z * (1.0f/256.0f); H.tri[g][3][2] = sC.w * (1.0f/256.0f);
      }
      if (l < 4) {
        float s = 0;
        for (int hh = 0; hh < 32; ++hh) {
          float z = cpb1[l * 32 + hh];
          #pragma unroll
          for (int d = 0; d < 3; ++d) z += H.tri[g][l][d] * cpW1[(l * 32 + hh) * 3 + d];
          z = fmaxf(z, 0.0f);
          s += z * cpw2[l * 32 + hh];
        }
        H.cps[g][l] = s + cpb2[l];
      }
    }
    #pragma unroll 1
    for (int j = 0; j < 4; ++j) {
      __syncthreads();
      for (int idx = t; idx < 8192; idx += 1024) {
        H.Wl[idx >> 8][idx & 255] = sW1[(size_t)(j * 32 + (idx >> 8)) * 256 + (idx & 255)];
      }
      const float* sarr = (j == 0) ? seed_ic : (j == 1) ? seed_sir : (j == 2) ? seed_icc : seed_sirc;
      for (int idx = t; idx < 2048; idx += 1024) {
        H.seedsl[idx >> 8][idx & 255] = sarr[(size_t)(b0 + (idx >> 8)) * 256 + (idx & 255)];
      }
      __syncthreads();
      int bb = t >> 7, o = (t >> 2) & 31, kq = t & 3;
      float d = 0.f;
      #pragma unroll
      for (int kk = 0; kk < 64; kk += 4) {
        float4 w = *(const float4*)&H.Wl[o][kq * 64 + kk];
        float4 s = *(const float4*)&H.seedsl[bb][kq * 64 + kk];
        d += w.x * s.x + w.y * s.y + w.z * s.z + w.w * s.w;
      }
      d += __shfl_xor(d, 1);
      d += __shfl_xor(d, 2);
      if (kq == 0) {
        float z = fmaxf(d + sb1[j * 32 + o], 0.0f);
        H.hbuf2[bb][j * 32 + o] = z * sw2[j * 32 + o];
      }
    }
    __syncthreads();
    if (act && l < 4) {
      float s = 0;
      #pragma unroll
      for (int hh = 0; hh < 32; ++hh) s += H.hbuf2[g][l * 32 + hh];
      H.seds[g][l] = s + sb2[l];
    }
    __syncthreads();
    float av2 = 0.0f;
    if (act && l < 32) {
      float z = fb1[l];
      #pragma unroll
      for (int d = 0; d < 10; ++d) {
        float cd = (d < 4) ? H.cps[g][d] : (d < 8) ? H.seds[g][d - 4] : scalars[b * 2 + (d - 8)];
        z += cd * fW1[l * 10 + d];
      }
      z = fmaxf(z, 0.0f);
      av2 = z * fw2[l];
    }
    #pragma unroll
    for (int off = 16; off > 0; off >>= 1) av2 += __shfl_down(av2, off);
    if (act && l == 0) out[b] = av2 + fb2[0];
  }
}

// ---------------- final combine ----------------
__global__ __launch_bounds__(64) void combine_kernel(const float* __restrict__ eig,
    const double* __restrict__ diffP, const double* __restrict__ offP, const double* __restrict__ trP,
    const float* __restrict__ valo, const float* __restrict__ vali,
    const double* __restrict__ smallp, float* __restrict__ out)
{
  int l = threadIdx.x;
  float vo = valo[l], vi = vali[l];
  float el = 0, el2 = 0;
  #pragma unroll
  for (int e = 0; e < 4; ++e) {
    el  += fabsf(vo - eig[l * 4 + e]);
    el2 += fabsf(vi - eig[(64 + l) * 4 + e]);
  }
  float lo_ = el * 0.25f + 0.2f * (float)(diffP[l] * (1.0/65536.0)) - 0.1f * (float)(offP[l] * (1.0/65536.0));
  float li_ = el2 * 0.25f + 0.2f * (float)(diffP[64 + l] * (1.0/65536.0)) - 0.1f * (float)(offP[64 + l] * (1.0/65536.0));
  if (vo == 0.0f) lo_ = 0.0f;
  if (vi == 0.0f) li_ = 0.0f;
  float trb = (float)((trP[l] + trP[64 + l]) * (1.0/65536.0));
  #pragma unroll
  for (int off = 32; off > 0; off >>= 1) {
    lo_ += __shfl_down(lo_, off);
    li_ += __shfl_down(li_, off);
    trb += __shfl_down(trb, off);
  }
  if (l == 0) {
    out[64] = lo_ * (1.0f / 64.0f);
    out[65] = li_ * (1.0f / 64.0f);
    out[66] = (float)(smallp[0] / (64.0 * 6.0 * 65536.0));
    out[67] = 0.5f * (float)smallp[1] + 0.5f * (trb * (1.0f / 64.0f));
  }
}

extern "C" void kernel_launch(void* const* d_in, const int* in_sizes, int n_in,
                              void* d_out, int out_size, void* d_ws, size_t ws_size,
                              hipStream_t stream) {
  (void)in_sizes; (void)n_in; (void)out_size; (void)ws_size;
  const float* ti       = (const float*)d_in[0];
  const float* seed_ic  = (const float*)d_in[1];
  const float* seed_sir = (const float*)d_in[2];
  const float* seed_icc = (const float*)d_in[3];
  const float* seed_sirc= (const float*)d_in[4];
  const float* scalars  = (const float*)d_in[5];
  const float* valo     = (const float*)d_in[6];
  const float* vali     = (const float*)d_in[7];
  const float* S1p      = (const float*)d_in[8];
  const float* S2p      = (const float*)d_in[9];
  const float* S3p      = (const float*)d_in[10];
  const float* S4p      = (const float*)d_in[11];
  const float* cpA      = (const float*)d_in[12];
  const float* cpB      = (const float*)d_in[13];
  const float* cpC      = (const float*)d_in[14];
  const float* cpW1     = (const float*)d_in[15];
  const float* cpb1     = (const float*)d_in[16];
  const float* cpw2     = (const float*)d_in[17];
  const float* cpb2     = (const float*)d_in[18];
  const float* sW1      = (const float*)d_in[19];
  const float* sb1      = (const float*)d_in[20];
  const float* sw2      = (const float*)d_in[21];
  const float* sb2      = (const float*)d_in[22];
  const float* fW1      = (const float*)d_in[23];
  const float* fb1      = (const float*)d_in[24];
  const float* fw2      = (const float*)d_in[25];
  const float* fb2      = (const float*)d_in[26];

  char* ws = (char*)d_ws;
  ushort_t* Q0     = (ushort_t*)(ws + OFF_Q0);
  ushort_t* Q1     = (ushort_t*)(ws + OFF_Q1);
  ushort_t* Zb     = (ushort_t*)(ws + OFF_ZB);
  float*    eig    = (float*)(ws + OFF_EIG);
  double*   diffP  = (double*)(ws + OFF_DIFFP);
  double*   offP   = (double*)(ws + OFF_OFFP);
  double*   trP    = (double*)(ws + OFF_TRP);
  double*   smallp = (double*)(ws + OFF_SMALL);
  float*    out    = (float*)d_out;

  dim3 gg(2, 2, 128), gb(256);
  const size_t S6 = 6ull * 65536ull, S1b = 65536ull;
  gemm_mfma<false, 2, true, false><<<gg, gb, 0, stream>>>(
      (const void*)(ti + 0 * 65536), (const void*)(ti + 2 * 65536), S6,
      (const void*)S1p, (const void*)S3p, 0,
      (void*)Q0, S1b, nullptr, nullptr, 0, smallp, diffP, offP, trP);
  gemm_mfma<true, 2, false, false><<<gg, gb, 0, stream>>>(
      (const void*)Q0, (const void*)(Q0 + 64 * 65536), S1b,
      (const void*)(ti + 4 * 65536), (const void*)(ti + 5 * 65536), S6,
      (void*)Q1, S1b, nullptr, nullptr, 0, smallp, diffP, offP, trP);
  gemm_mfma<true, 2, false, false><<<gg, gb, 0, stream>>>(
      (const void*)Q1, (const void*)(Q1 + 64 * 65536), S1b,
      (const void*)S2p, (const void*)S4p, 0,
      (void*)Q0, S1b, nullptr, nullptr, 0, smallp, diffP, offP, trP);
  gemm_mfma<true, 1, false, true><<<gg, gb, 0, stream>>>(
      (const void*)Q0, (const void*)(Q0 + 64 * 65536), S1b,
      (const void*)(ti + 3 * 65536), (const void*)(ti + 1 * 65536), S6,
      (void*)Zb, S1b,
      ti + 4 * 65536, ti + 5 * 65536, S6, smallp, diffP, offP, trP);

  mega_kernel<<<256, 1024, 0, stream>>>(
      eig, ti, Zb, cpA, cpB, cpC, smallp,
      S1p, S2p, S3p, S4p,
      seed_ic, seed_sir, seed_icc, seed_sirc, scalars,
      cpW1, cpb1, cpw2, cpb2, sW1, sb1, sw2, sb2,
      fW1, fb1, fw2, fb2, out);

  combine_kernel<<<1, 64, 0, stream>>>(eig, diffP, offP, trP, valo, vali, smallp, out);
}

// Round 21
// 130.874 us; speedup vs baseline: 1.0467x; 1.0467x over previous
//
#include <hip/hip_runtime.h>
#include <hip/hip_fp16.h>

#define LM 20

// ---------------- ws layout (bytes) ----------------
#define OFF_Q0    16777216ull
#define OFF_Q1    33554432ull
#define OFF_ZB    33554432ull             // Zb overwrites Q1 after G3
#define OFF_EIG   50331648ull
#define OFF_DIFFP (OFF_EIG + 4096ull)
#define OFF_OFFP  (OFF_DIFFP + 1024ull)
#define OFF_TRP   (OFF_OFFP + 1024ull)
#define OFF_SMALL (OFF_TRP + 1024ull)

typedef unsigned short ushort_t;
typedef short bf16x8 __attribute__((ext_vector_type(8)));
typedef float f32x4 __attribute__((ext_vector_type(4)));

static __device__ __forceinline__ ushort_t f2bf(float f) {
  unsigned u = __float_as_uint(f);
  unsigned r = (u + 0x7fffu + ((u >> 16) & 1u)) >> 16;
  return (ushort_t)r;
}
static __device__ __forceinline__ unsigned packbf(float a, float b) {
  return (unsigned)f2bf(a) | ((unsigned)f2bf(b) << 16);
}
static __device__ __forceinline__ float bflo(unsigned u) { return __uint_as_float(u << 16); }
static __device__ __forceinline__ float bfhi(unsigned u) { return __uint_as_float(u & 0xffff0000u); }
static __device__ __forceinline__ float b2f(ushort_t u) { return __uint_as_float(((unsigned)u) << 16); }
static __device__ __forceinline__ __half2 u2h2(unsigned u) { __half2 r; *reinterpret_cast<unsigned*>(&r) = u; return r; }
static __device__ __forceinline__ unsigned packh2(float a, float b) {
  return (unsigned)__half_as_ushort(__float2half_rn(a)) |
         ((unsigned)__half_as_ushort(__float2half_rn(b)) << 16);
}

// ---------------- MFMA GEMM, 128x128 tile, BK=32, 128 batches (split bases at b=64) ----------------
template<bool ABF, int BMODE, bool INITP, bool REDUCE>
__global__ __launch_bounds__(256) void gemm_mfma(
    const void* __restrict__ A0, const void* __restrict__ A1, size_t sA,
    const void* __restrict__ B0, const void* __restrict__ B1, size_t sB,
    void* __restrict__ Cbase, size_t sC,
    const float* __restrict__ Zr0, const float* __restrict__ Zr1, size_t sZr,
    double* __restrict__ smallp, double* __restrict__ diffP,
    double* __restrict__ offP, double* __restrict__ trP)
{
  __shared__ ushort_t At[128][40];
  __shared__ ushort_t Bt[128][40];
  __shared__ float redsh[4][3];
  const int t = threadIdx.x;
  if (INITP && blockIdx.x == 0 && blockIdx.y == 0 && blockIdx.z == 0) {
    if (t < 2) smallp[t] = 0.0;
    if (t < 128) { diffP[t] = 0.0; offP[t] = 0.0; trP[t] = 0.0; }
  }
  const int b = blockIdx.z;
  const int bl = (b < 64) ? b : b - 64;
  const void* Ab_ = (b < 64) ? A0 : A1;
  const void* Bb_ = (b < 64) ? B0 : B1;
  const int tm = blockIdx.y * 128, tn = blockIdx.x * 128;
  const int w = t >> 6, l = t & 63;
  const int wr = w >> 1, wc = w & 1;
  const int fr = l & 15, kc = l >> 4;

  f32x4 acc[4][4] = {};

  for (int s8 = 0; s8 < 8; ++s8) {
    const int k0 = s8 << 5;
    #pragma unroll
    for (int cc = 0; cc < 2; ++cc) {
      int c = t + cc * 256;
      int row = c >> 2, q = c & 3;
      if (ABF) {
        const ushort_t* Ap = (const ushort_t*)Ab_ + (size_t)bl * sA + (size_t)(tm + row) * 256 + k0 + q * 8;
        *(uint4*)&At[row][q * 8] = *(const uint4*)Ap;
      } else {
        const float* Ap = (const float*)Ab_ + (size_t)bl * sA + (size_t)(tm + row) * 256 + k0 + q * 8;
        float4 f0 = *(const float4*)Ap, f1 = *(const float4*)(Ap + 4);
        uint4 u;
        u.x = packbf(f0.x, f0.y); u.y = packbf(f0.z, f0.w);
        u.z = packbf(f1.x, f1.y); u.w = packbf(f1.z, f1.w);
        *(uint4*)&At[row][q * 8] = u;
      }
    }
    if (BMODE == 1) {
      #pragma unroll
      for (int cc = 0; cc < 2; ++cc) {
        int c = t + cc * 256;
        int row = c >> 2, q = c & 3;
        const float* Bp = (const float*)Bb_ + (size_t)bl * sB + (size_t)(tn + row) * 256 + k0 + q * 8;
        float4 f0 = *(const float4*)Bp, f1 = *(const float4*)(Bp + 4);
        uint4 u;
        u.x = packbf(f0.x, f0.y); u.y = packbf(f0.z, f0.w);
        u.z = packbf(f1.x, f1.y); u.w = packbf(f1.z, f1.w);
        *(uint4*)&Bt[row][q * 8] = u;
      }
    } else {
      int k2 = t & 15, c = t >> 4;
      const float* Bp0 = (const float*)Bb_ + (size_t)bl * sB + (size_t)(k0 + 2 * k2) * 256 + tn + c * 8;
      const float* Bp1 = Bp0 + 256;
      float4 a0 = *(const float4*)Bp0, a1 = *(const float4*)(Bp0 + 4);
      float4 c0v = *(const float4*)Bp1, c1v = *(const float4*)(Bp1 + 4);
      float lo[8] = {a0.x,a0.y,a0.z,a0.w,a1.x,a1.y,a1.z,a1.w};
      float hi[8] = {c0v.x,c0v.y,c0v.z,c0v.w,c1v.x,c1v.y,c1v.z,c1v.w};
      unsigned* Bd = (unsigned*)&Bt[0][0];
      #pragma unroll
      for (int i = 0; i < 8; ++i) {
        int n = c * 8 + i;
        Bd[n * 20 + k2] = packbf(lo[i], hi[i]);
      }
    }
    __syncthreads();
    bf16x8 af[4], bfv[4];
    #pragma unroll
    for (int i = 0; i < 4; ++i) af[i] = *(const bf16x8*)&At[wr * 64 + i * 16 + fr][kc * 8];
    #pragma unroll
    for (int jj = 0; jj < 4; ++jj) bfv[jj] = *(const bf16x8*)&Bt[wc * 64 + jj * 16 + fr][kc * 8];
    #pragma unroll
    for (int i = 0; i < 4; ++i) {
      #pragma unroll
      for (int jj = 0; jj < 4; ++jj) {
        acc[i][jj] = __builtin_amdgcn_mfma_f32_16x16x32_bf16(af[i], bfv[jj], acc[i][jj], 0, 0, 0);
      }
    }
    __syncthreads();
  }

  ushort_t* Cp = (ushort_t*)Cbase + (size_t)b * sC;
  #pragma unroll
  for (int i = 0; i < 4; ++i) {
    #pragma unroll
    for (int q = 0; q < 4; ++q) {
      size_t rbase = (size_t)(tm + wr * 64 + i * 16 + kc * 4 + q) * 256;
      #pragma unroll
      for (int jj = 0; jj < 4; ++jj) {
        Cp[rbase + tn + wc * 64 + jj * 16 + fr] = f2bf(acc[i][jj][q]);
      }
    }
  }

  if (REDUCE) {
    const float* Zr_ = ((b < 64) ? Zr0 : Zr1) + (size_t)bl * sZr;
    float pd = 0.f, po = 0.f, ptr = 0.f;
    #pragma unroll
    for (int i = 0; i < 4; ++i) {
      #pragma unroll
      for (int q = 0; q < 4; ++q) {
        int row = tm + wr * 64 + i * 16 + kc * 4 + q;
        const float* ZrRow = Zr_ + (size_t)row * 256 + tn + wc * 64;
        #pragma unroll
        for (int jj = 0; jj < 4; ++jj) {
          int col = tn + wc * 64 + jj * 16 + fr;
          float c = acc[i][jj][q];
          float zr = ZrRow[jj * 16 + fr];
          bool diag = (row == col);
          pd += fabsf(c - (diag ? 1.0f : 0.0f));
          po += diag ? 0.0f : fabsf(c);
          ptr += fabsf(c - zr);
        }
      }
    }
    #pragma unroll
    for (int off = 32; off > 0; off >>= 1) {
      pd += __shfl_down(pd, off);
      po += __shfl_down(po, off);
      ptr += __shfl_down(ptr, off);
    }
    if (l == 0) { redsh[w][0] = pd; redsh[w][1] = po; redsh[w][2] = ptr; }
    __syncthreads();
    if (t == 0) {
      atomicAdd(&diffP[b], (double)(redsh[0][0] + redsh[1][0] + redsh[2][0] + redsh[3][0]));
      atomicAdd(&offP[b],  (double)(redsh[0][1] + redsh[1][1] + redsh[2][1] + redsh[3][1]));
      atomicAdd(&trP[b],   (double)(redsh[0][2] + redsh[1][2] + redsh[2][2] + redsh[3][2]));
    }
  }
}

// ====== MEGA: lanczos (0..127, fused symmetrize) | cp (128..243) | sreg (244..247) | head (248..255) ======
struct LanSh {
  ushort_t Zl[256][260];   // padded bf16 matrix (520B rows: uint reads 4-way, col reads conflict-free)
  unsigned vpack[128];
  float wtmp[4][256];
  float red2[4][2];
  float red1[16];
  float alpha[LM];
  float betaArr[LM + 1];
  float beta2arr[LM + 1];
};
struct CpSh { float Bsh[4][256][4]; float Csh[4][256][4]; double red[4][256]; };
struct SregSh { double red[4][256]; };
struct HeadSh {
  float Wl[32][258];
  float seedsl[8][256];
  float hbuf2[8][128];
  float tri[8][4][3];
  float cps[8][4];
  float seds[8][4];
};
union MegaSh { LanSh lan; CpSh cp; SregSh sreg; HeadSh head; };

__global__ __launch_bounds__(1024, 1) void mega_kernel(
    float* __restrict__ eig,
    const float* __restrict__ ti, const ushort_t* __restrict__ Zb,
    const float* __restrict__ cpA, const float* __restrict__ cpB, const float* __restrict__ cpC,
    double* __restrict__ smallp,
    const float* __restrict__ S1, const float* __restrict__ S2,
    const float* __restrict__ S3, const float* __restrict__ S4,
    const float* __restrict__ seed_ic, const float* __restrict__ seed_sir,
    const float* __restrict__ seed_icc, const float* __restrict__ seed_sirc,
    const float* __restrict__ scalars,
    const float* __restrict__ cpW1, const float* __restrict__ cpb1,
    const float* __restrict__ cpw2, const float* __restrict__ cpb2,
    const float* __restrict__ sW1, const float* __restrict__ sb1,
    const float* __restrict__ sw2, const float* __restrict__ sb2,
    const float* __restrict__ fW1, const float* __restrict__ fb1,
    const float* __restrict__ fw2, const float* __restrict__ fb2,
    float* __restrict__ out)
{
  __shared__ MegaSh sh;
  const int bid = blockIdx.x;
  const int t = threadIdx.x;

  if (bid < 128) {
    // ---------------- Lanczos with in-block symmetrize ----------------
    int lane = t & 63, w16 = t >> 6;
    int r = t & 255, h = t >> 8;
    int mtx = bid;
    const ushort_t* Zm = Zb + (size_t)mtx * 65536;

    // stage Zb[mtx] into padded LDS, row-coalesced (uint2 = 4 ushorts per op)
    #pragma unroll
    for (int it = 0; it < 16; ++it) {
      int idx = t + it * 1024;               // 0..16383
      int row = idx >> 6, c4 = (idx & 63) << 2;
      *(uint2*)&sh.lan.Zl[row][c4] = *(const uint2*)(Zm + (size_t)row * 256 + c4);
    }
    __syncthreads();

    // build m[32] = packed f16 of (Z[r][c] + Z[c][r]) * SC, cols h*64..h*64+63
    const float SC = 0.5f * 0.015625f;
    unsigned m[32];
    #pragma unroll
    for (int q = 0; q < 32; ++q) {
      int c0 = h * 64 + 2 * q;
      unsigned a = *(const unsigned*)&sh.lan.Zl[r][c0];
      float b0v = b2f(sh.lan.Zl[c0][r]);
      float b1v = b2f(sh.lan.Zl[c0 + 1][r]);
      m[q] = packh2((bflo(a) + b0v) * SC, (bfhi(a) + b1v) * SC);
    }
    __syncthreads();   // Zl dead; LanSh small arrays remain

    unsigned u0 = (unsigned)r * 1103515245u + 12345u;
    float r0v = 0.05f + (float)((u0 >> 9) & 0x7FFF) * (1.0f / 32768.0f);
    float vt = 0.0f, vprev = 0.0f;
    {
      float nv = r0v * r0v;
      #pragma unroll
      for (int off = 32; off > 0; off >>= 1) nv += __shfl_down(nv, off);
      if (lane == 0) sh.lan.red1[w16] = nv;
    }
    __syncthreads();
    {
      float nrm2 = sh.lan.red1[0] + sh.lan.red1[1] + sh.lan.red1[2] + sh.lan.red1[3];
      vt = r0v * rsqrtf(nrm2);
      if (h == 0) {
        float vo = __shfl_down(vt, 1);
        if ((lane & 1) == 0) sh.lan.vpack[t >> 1] = packh2(vt, vo);
      }
    }
    __syncthreads();

    const uint4* vp4 = (const uint4*)sh.lan.vpack;
    float2* red2 = (float2*)&sh.lan.red2[0][0];
    float beta_prev = 0.0f;
    int meff = LM;
    for (int j = 0; j < LM; ++j) {
      __half2 h0v = u2h2(0u), h1v = u2h2(0u), h2v = u2h2(0u), h3v = u2h2(0u);
      #pragma unroll
      for (int q = 0; q < 8; ++q) {
        uint4 vu = vp4[h * 8 + q];
        h0v = __hfma2(u2h2(m[4 * q + 0]), u2h2(vu.x), h0v);
        h1v = __hfma2(u2h2(m[4 * q + 1]), u2h2(vu.y), h1v);
        h2v = __hfma2(u2h2(m[4 * q + 2]), u2h2(vu.z), h2v);
        h3v = __hfma2(u2h2(m[4 * q + 3]), u2h2(vu.w), h3v);
      }
      float2 f0 = __half22float2(h0v), f1 = __half22float2(h1v);
      float2 f2 = __half22float2(h2v), f3 = __half22float2(h3v);
      sh.lan.wtmp[h][r] = ((f0.x + f0.y) + (f1.x + f1.y)) + ((f2.x + f2.y) + (f3.x + f3.y));
      float wt = 0.0f;
      __syncthreads();                                      // B1
      if (h == 0) {
        wt = sh.lan.wtmp[0][r] + sh.lan.wtmp[1][r] + sh.lan.wtmp[2][r] + sh.lan.wtmp[3][r];
        float s1 = wt * vt, s3 = wt * wt;
        #pragma unroll
        for (int off = 32; off > 0; off >>= 1) {
          s1 += __shfl_down(s1, off);
          s3 += __shfl_down(s3, off);
        }
        if (lane == 0) red2[w16] = make_float2(s1, s3);
      }
      __syncthreads();                                      // B2
      float2 p0 = red2[0], p1 = red2[1], p2 = red2[2], p3 = red2[3];
      float S1v = ((p0.x + p1.x) + (p2.x + p3.x));
      float S3v = ((p0.y + p1.y) + (p2.y + p3.y));
      float bn2 = S3v - S1v * S1v - beta_prev * beta_prev;
      float bn = sqrtf(fmaxf(bn2, 1e-30f));
      if (t == 0) { sh.lan.alpha[j] = S1v; sh.lan.betaArr[j + 1] = bn; sh.lan.beta2arr[j + 1] = bn * bn; }
      if (bn < 1e-6f * (fabsf(S1v) + 1.0f)) { meff = j + 1; break; }
      if (h == 0) {
        float wn = (wt - S1v * vt - beta_prev * vprev) / bn;
        vprev = vt; vt = wn;
        float vo = __shfl_down(vt, 1);
        if ((lane & 1) == 0) sh.lan.vpack[t >> 1] = packh2(vt, vo);
      }
      beta_prev = bn;
      __syncthreads();                                      // B3
    }
    __syncthreads();

    if (w16 < 4) {
      float lo = 1e30f, hi = -1e30f;
      for (int i = 0; i < meff; ++i) {
        float bl = (i > 0) ? sh.lan.betaArr[i] : 0.0f;
        float bu = (i + 1 < meff) ? sh.lan.betaArr[i + 1] : 0.0f;
        lo = fminf(lo, sh.lan.alpha[i] - bl - bu);
        hi = fmaxf(hi, sh.lan.alpha[i] + bl + bu);
      }
      int q = w16 + 1; if (q > meff - 1) q = meff - 1;
      #pragma unroll
      for (int rr = 0; rr < 3; ++rr) {
        float step = (hi - lo) * (1.0f / 65.0f);
        float mid = lo + step * (float)(lane + 1);
        int cnt = 0;
        float d = sh.lan.alpha[0] - mid;
        if (fabsf(d) < 1e-20f) d = -1e-20f;
        cnt += (d < 0.0f);
        for (int i = 1; i < meff; ++i) {
          d = sh.lan.alpha[i] - mid - sh.lan.beta2arr[i] / d;
          if (fabsf(d) < 1e-20f) d = -1e-20f;
          cnt += (d < 0.0f);
        }
        unsigned long long mask = __ballot(cnt >= q + 1);
        if (mask == 0ULL) {
          lo = lo + step * 64.0f;
        } else {
          int idx = __ffsll(mask) - 1;
          float nlo = lo + step * (float)idx;
          hi = lo + step * (float)(idx + 1);
          lo = nlo;
        }
      }
      if (lane == 0) eig[mtx * 4 + w16] = 32.0f * (lo + hi);
    }
  } else if (bid < 244) {
    // ---------------- CP loss: 116 blocks x 4 groups; units 0..383 flat-mapped with guard ----------------
    int g = t >> 8, tid = t & 255;
    int unit = (bid - 128) * 4 + g;
    bool live = (unit < 384);
    int b = live ? (unit / 6) : 0;
    int i = live ? (unit - b * 6) : 0;
    float (*Bsh)[4] = sh.cp.Bsh[g];
    float (*Csh)[4] = sh.cp.Csh[g];
    double* red = sh.cp.red[g];
    if (live) {
      *(float4*)&Bsh[tid][0] = *(const float4*)(cpB + ((size_t)b * 256 + tid) * 4);
      *(float4*)&Csh[tid][0] = *(const float4*)(cpC + ((size_t)b * 256 + tid) * 4);
    }
    float a0 = live ? cpA[((size_t)b * 6 + i) * 4 + 0] : 0.f;
    float a1 = live ? cpA[((size_t)b * 6 + i) * 4 + 1] : 0.f;
    float a2 = live ? cpA[((size_t)b * 6 + i) * 4 + 2] : 0.f;
    float a3 = live ? cpA[((size_t)b * 6 + i) * 4 + 3] : 0.f;
    __syncthreads();
    double acc0 = 0, acc1 = 0;
    if (live) {
      float c0 = Csh[tid][0], c1 = Csh[tid][1], c2 = Csh[tid][2], c3 = Csh[tid][3];
      if (i < 4) {
        const float* T = ti + ((size_t)b * 6 + i) * 65536;
        #pragma unroll 4
        for (int j = 0; j < 256; j += 2) {
          float4 bj0 = *(const float4*)&Bsh[j][0];
          float4 bj1 = *(const float4*)&Bsh[j + 1][0];
          float r0 = a0 * bj0.x * c0 + a1 * bj0.y * c1 + a2 * bj0.z * c2 + a3 * bj0.w * c3;
          float r1 = a0 * bj1.x * c0 + a1 * bj1.y * c1 + a2 * bj1.z * c2 + a3 * bj1.w * c3;
          float d0 = r0 - T[(size_t)j * 256 + tid];
          float d1 = r1 - T[(size_t)(j + 1) * 256 + tid];
          acc0 += (double)d0 * (double)d0;
          acc1 += (double)d1 * (double)d1;
        }
      } else {
        const ushort_t* T = Zb + (size_t)((i == 4) ? b : 64 + b) * 65536;
        #pragma unroll 4
        for (int j = 0; j < 256; j += 2) {
          float4 bj0 = *(const float4*)&Bsh[j][0];
          float4 bj1 = *(const float4*)&Bsh[j + 1][0];
          float r0 = a0 * bj0.x * c0 + a1 * bj0.y * c1 + a2 * bj0.z * c2 + a3 * bj0.w * c3;
          float r1 = a0 * bj1.x * c0 + a1 * bj1.y * c1 + a2 * bj1.z * c2 + a3 * bj1.w * c3;
          float d0 = r0 - b2f(T[(size_t)j * 256 + tid]);
          float d1 = r1 - b2f(T[(size_t)(j + 1) * 256 + tid]);
          acc0 += (double)d0 * (double)d0;
          acc1 += (double)d1 * (double)d1;
        }
      }
    }
    red[tid] = acc0 + acc1; __syncthreads();
    #pragma unroll
    for (int s = 128; s > 0; s >>= 1) { if (tid < s) red[tid] += red[tid + s]; __syncthreads(); }
    if (live && tid == 0) atomicAdd(&smallp[0], red[0]);
  } else if (bid < 248) {
    int g = t >> 8, tid = t & 255;
    int slot = (bid - 244) * 4 + g;
    int mnum = slot >> 2, quarter = slot & 3;
    const float* S = (mnum == 0) ? S1 : (mnum == 1) ? S2 : (mnum == 2) ? S3 : S4;
    double* red = sh.sreg.red[g];
    double tot = 0;
    int base = quarter * 16384;
    #pragma unroll 4
    for (int e = base + tid; e < base + 16384; e += 256) {
      int i = e >> 8, j = e & 255;
      float a = S[e];
      tot += (double)fabsf(a - (i == j ? 1.0f : 0.0f));
      if (i != j) tot += (double)fabsf(a);
    }
    red[tid] = tot; __syncthreads();
    #pragma unroll
    for (int s = 128; s > 0; s >>= 1) { if (tid < s) red[tid] += red[tid + s]; __syncthreads(); }
    if (tid == 0) atomicAdd(&smallp[1], -red[0] / 65536.0);
  } else {
    HeadSh& H = sh.head;
    const int b0 = (bid - 248) * 8;
    const int g = t >> 6, l = t & 63;
    const bool act = g < 8;
    const int b = b0 + (act ? g : 0);
    if (act) {
      if (l < 4) {
        float s = 0;
        #pragma unroll
        for (int i = 0; i < 6; ++i) s += cpA[((size_t)b * 6 + i) * 4 + l];
        H.tri[g][l][0] = s * (1.0f / 6.0f);
      }
      float4 sB = make_float4(0,0,0,0), sC = make_float4(0,0,0,0);
      for (int j = l; j < 256; j += 64) {
        float4 v = *(const float4*)(cpB + ((size_t)b * 256 + j) * 4);
        sB.x += v.x; sB.y += v.y; sB.z += v.z; sB.w += v.w;
        float4 w = *(const float4*)(cpC + ((size_t)b * 256 + j) * 4);
        sC.x += w.x; sC.y += w.y; sC.z += w.z; sC.w += w.w;
      }
      #pragma unroll
      for (int off = 32; off > 0; off >>= 1) {
        sB.x += __shfl_down(sB.x, off); sB.y += __shfl_down(sB.y, off);
        sB.z += __shfl_down(sB.z, off); sB.w += __shfl_down(sB.w, off);
        sC.x += __shfl_down(sC.x, off); sC.y += __shfl_down(sC.y, off);
        sC.z += __shfl_down(sC.z, off); sC.w += __shfl_down(sC.w, off);
      }
      if (l == 0) {
        H.tri[g][0][1] = sB.x * (1.0f/256.0f); H.tri[g][1][1] = sB.y * (1.0f/256.0f);
        H.tri[g][2][1] = sB.z * (1.0f/256.0f); H.tri[g][3][1] = sB.w * (1.0f/256.0f);
        H.tri[g][0][2] = sC.x * (1.0f/256.0f); H.tri[g][1][2] = sC.y * (1.0f/256.0f);
        H.tri[g][2][2] = sC.z * (1.0f/256.0f); H.tri[g][3][2] = sC.w * (1.0f/256.0f);
      }
      if (l < 4) {
        float s = 0;
        for (int hh = 0; hh < 32; ++hh) {
          float z = cpb1[l * 32 + hh];
          #pragma unroll
          for (int d = 0; d < 3; ++d) z += H.tri[g][l][d] * cpW1[(l * 32 + hh) * 3 + d];
          z = fmaxf(z, 0.0f);
          s += z * cpw2[l * 32 + hh];
        }
        H.cps[g][l] = s + cpb2[l];
      }
    }
    #pragma unroll 1
    for (int j = 0; j < 4; ++j) {
      __syncthreads();
      for (int idx = t; idx < 8192; idx += 1024) {
        H.Wl[idx >> 8][idx & 255] = sW1[(size_t)(j * 32 + (idx >> 8)) * 256 + (idx & 255)];
      }
      const float* sarr = (j == 0) ? seed_ic : (j == 1) ? seed_sir : (j == 2) ? seed_icc : seed_sirc;
      for (int idx = t; idx < 2048; idx += 1024) {
        H.seedsl[idx >> 8][idx & 255] = sarr[(size_t)(b0 + (idx >> 8)) * 256 + (idx & 255)];
      }
      __syncthreads();
      int bb = t >> 7, o = (t >> 2) & 31, kq = t & 3;
      float d = 0.f;
      #pragma unroll
      for (int kk = 0; kk < 64; kk += 4) {
        float4 w = *(const float4*)&H.Wl[o][kq * 64 + kk];
        float4 s = *(const float4*)&H.seedsl[bb][kq * 64 + kk];
        d += w.x * s.x + w.y * s.y + w.z * s.z + w.w * s.w;
      }
      d += __shfl_xor(d, 1);
      d += __shfl_xor(d, 2);
      if (kq == 0) {
        float z = fmaxf(d + sb1[j * 32 + o], 0.0f);
        H.hbuf2[bb][j * 32 + o] = z * sw2[j * 32 + o];
      }
    }
    __syncthreads();
    if (act && l < 4) {
      float s = 0;
      #pragma unroll
      for (int hh = 0; hh < 32; ++hh) s += H.hbuf2[g][l * 32 + hh];
      H.seds[g][l] = s + sb2[l];
    }
    __syncthreads();
    float av2 = 0.0f;
    if (act && l < 32) {
      float z = fb1[l];
      #pragma unroll
      for (int d = 0; d < 10; ++d) {
        float cd = (d < 4) ? H.cps[g][d] : (d < 8) ? H.seds[g][d - 4] : scalars[b * 2 + (d - 8)];
        z += cd * fW1[l * 10 + d];
      }
      z = fmaxf(z, 0.0f);
      av2 = z * fw2[l];
    }
    #pragma unroll
    for (int off = 16; off > 0; off >>= 1) av2 += __shfl_down(av2, off);
    if (act && l == 0) out[b] = av2 + fb2[0];
  }
}

// ---------------- final combine ----------------
__global__ __launch_bounds__(64) void combine_kernel(const float* __restrict__ eig,
    const double* __restrict__ diffP, const double* __restrict__ offP, const double* __restrict__ trP,
    const float* __restrict__ valo, const float* __restrict__ vali,
    const double* __restrict__ smallp, float* __restrict__ out)
{
  int l = threadIdx.x;
  float vo = valo[l], vi = vali[l];
  float el = 0, el2 = 0;
  #pragma unroll
  for (int e = 0; e < 4; ++e) {
    el  += fabsf(vo - eig[l * 4 + e]);
    el2 += fabsf(vi - eig[(64 + l) * 4 + e]);
  }
  float lo_ = el * 0.25f + 0.2f * (float)(diffP[l] * (1.0/65536.0)) - 0.1f * (float)(offP[l] * (1.0/65536.0));
  float li_ = el2 * 0.25f + 0.2f * (float)(diffP[64 + l] * (1.0/65536.0)) - 0.1f * (float)(offP[64 + l] * (1.0/65536.0));
  if (vo == 0.0f) lo_ = 0.0f;
  if (vi == 0.0f) li_ = 0.0f;
  float trb = (float)((trP[l] + trP[64 + l]) * (1.0/65536.0));
  #pragma unroll
  for (int off = 32; off > 0; off >>= 1) {
    lo_ += __shfl_down(lo_, off);
    li_ += __shfl_down(li_, off);
    trb += __shfl_down(trb, off);
  }
  if (l == 0) {
    out[64] = lo_ * (1.0f / 64.0f);
    out[65] = li_ * (1.0f / 64.0f);
    out[66] = (float)(smallp[0] / (64.0 * 6.0 * 65536.0));
    out[67] = 0.5f * (float)smallp[1] + 0.5f * (trb * (1.0f / 64.0f));
  }
}

extern "C" void kernel_launch(void* const* d_in, const int* in_sizes, int n_in,
                              void* d_out, int out_size, void* d_ws, size_t ws_size,
                              hipStream_t stream) {
  (void)in_sizes; (void)n_in; (void)out_size; (void)ws_size;
  const float* ti       = (const float*)d_in[0];
  const float* seed_ic  = (const float*)d_in[1];
  const float* seed_sir = (const float*)d_in[2];
  const float* seed_icc = (const float*)d_in[3];
  const float* seed_sirc= (const float*)d_in[4];
  const float* scalars  = (const float*)d_in[5];
  const float* valo     = (const float*)d_in[6];
  const float* vali     = (const float*)d_in[7];
  const float* S1p      = (const float*)d_in[8];
  const float* S2p      = (const float*)d_in[9];
  const float* S3p      = (const float*)d_in[10];
  const float* S4p      = (const float*)d_in[11];
  const float* cpA      = (const float*)d_in[12];
  const float* cpB      = (const float*)d_in[13];
  const float* cpC      = (const float*)d_in[14];
  const float* cpW1     = (const float*)d_in[15];
  const float* cpb1     = (const float*)d_in[16];
  const float* cpw2     = (const float*)d_in[17];
  const float* cpb2     = (const float*)d_in[18];
  const float* sW1      = (const float*)d_in[19];
  const float* sb1      = (const float*)d_in[20];
  const float* sw2      = (const float*)d_in[21];
  const float* sb2      = (const float*)d_in[22];
  const float* fW1      = (const float*)d_in[23];
  const float* fb1      = (const float*)d_in[24];
  const float* fw2      = (const float*)d_in[25];
  const float* fb2      = (const float*)d_in[26];

  char* ws = (char*)d_ws;
  ushort_t* Q0     = (ushort_t*)(ws + OFF_Q0);
  ushort_t* Q1     = (ushort_t*)(ws + OFF_Q1);
  ushort_t* Zb     = (ushort_t*)(ws + OFF_ZB);
  float*    eig    = (float*)(ws + OFF_EIG);
  double*   diffP  = (double*)(ws + OFF_DIFFP);
  double*   offP   = (double*)(ws + OFF_OFFP);
  double*   trP    = (double*)(ws + OFF_TRP);
  double*   smallp = (double*)(ws + OFF_SMALL);
  float*    out    = (float*)d_out;

  dim3 gg(2, 2, 128), gb(256);
  const size_t S6 = 6ull * 65536ull, S1b = 65536ull;
  gemm_mfma<false, 2, true, false><<<gg, gb, 0, stream>>>(
      (const void*)(ti + 0 * 65536), (const void*)(ti + 2 * 65536), S6,
      (const void*)S1p, (const void*)S3p, 0,
      (void*)Q0, S1b, nullptr, nullptr, 0, smallp, diffP, offP, trP);
  gemm_mfma<true, 2, false, false><<<gg, gb, 0, stream>>>(
      (const void*)Q0, (const void*)(Q0 + 64 * 65536), S1b,
      (const void*)(ti + 4 * 65536), (const void*)(ti + 5 * 65536), S6,
      (void*)Q1, S1b, nullptr, nullptr, 0, smallp, diffP, offP, trP);
  gemm_mfma<true, 2, false, false><<<gg, gb, 0, stream>>>(
      (const void*)Q1, (const void*)(Q1 + 64 * 65536), S1b,
      (const void*)S2p, (const void*)S4p, 0,
      (void*)Q0, S1b, nullptr, nullptr, 0, smallp, diffP, offP, trP);
  gemm_mfma<true, 1, false, true><<<gg, gb, 0, stream>>>(
      (const void*)Q0, (const void*)(Q0 + 64 * 65536), S1b,
      (const void*)(ti + 3 * 65536), (const void*)(ti + 1 * 65536), S6,
      (void*)Zb, S1b,
      ti + 4 * 65536, ti + 5 * 65536, S6, smallp, diffP, offP, trP);

  mega_kernel<<<256, 1024, 0, stream>>>(
      eig, ti, Zb, cpA, cpB, cpC, smallp,
      S1p, S2p, S3p, S4p,
      seed_ic, seed_sir, seed_icc, seed_sirc, scalars,
      cpW1, cpb1, cpw2, cpb2, sW1, sb1, sw2, sb2,
      fW1, fb1, fw2, fb2, out);

  combine_kernel<<<1, 64, 0, stream>>>(eig, diffP, offP, trP, valo, vali, smallp, out);
}